// Round 7
// baseline (158.039 us; speedup 1.0000x reference)
//
#include <hip/hip_runtime.h>
#include <stdint.h>

// Shapes: B=8, Nt=Ns=1024, D=128, H=4. All I/O float32.

typedef float f32x16 __attribute__((ext_vector_type(16)));
typedef float f32x4 __attribute__((ext_vector_type(4)));
typedef short s16x8 __attribute__((ext_vector_type(8)));
typedef __bf16 bf16x8 __attribute__((ext_vector_type(8)));

__device__ __forceinline__ f32x16 mfma_bf16(s16x8 a, s16x8 b, f32x16 c) {
  return __builtin_amdgcn_mfma_f32_32x32x16_bf16(
      __builtin_bit_cast(bf16x8, a), __builtin_bit_cast(bf16x8, b), c, 0, 0, 0);
}
__device__ __forceinline__ f32x4 mfma16(s16x8 a, s16x8 b, f32x4 c) {
  return __builtin_amdgcn_mfma_f32_16x16x32_bf16(
      __builtin_bit_cast(bf16x8, a), __builtin_bit_cast(bf16x8, b), c, 0, 0, 0);
}

__device__ __forceinline__ unsigned short f2bf(float f) {
  union { float f; unsigned int i; } v; v.f = f;
  return (unsigned short)((v.i + 0x8000u) >> 16);
}
__device__ __forceinline__ float bf2f(unsigned short u) {
  union { unsigned int i; float f; } v; v.i = ((unsigned int)u) << 16; return v.f;
}
__device__ __forceinline__ s16x8 pack8(float4 a, float4 b) {
  s16x8 r;
  r[0] = (short)f2bf(a.x); r[1] = (short)f2bf(a.y);
  r[2] = (short)f2bf(a.z); r[3] = (short)f2bf(a.w);
  r[4] = (short)f2bf(b.x); r[5] = (short)f2bf(b.y);
  r[6] = (short)f2bf(b.z); r[7] = (short)f2bf(b.w);
  return r;
}
__device__ __forceinline__ f32x16 zero16() {
  f32x16 z;
#pragma unroll
  for (int i = 0; i < 16; ++i) z[i] = 0.f;
  return z;
}
__device__ __forceinline__ f32x4 zero4() {
  f32x4 z; z[0] = z[1] = z[2] = z[3] = 0.f; return z;
}

// ---------------- K_prep: csum (final) + FFN weight pack + W_src pack ----------------
__global__ __launch_bounds__(256) void k_prep(
    const float* __restrict__ W_tgt, const float* __restrict__ W_src,
    const float* __restrict__ att_tgt, const float* __restrict__ att_src,
    const float* __restrict__ W_gv, const float* __restrict__ W_out,
    float* __restrict__ ws_c, unsigned short* __restrict__ wpP,
    unsigned short* __restrict__ W_srcP) {
  int blk = blockIdx.x, tid = threadIdx.x;
  if (blk < 8) {
    // csum[which][h][k] = sum_d att[h][d] * W[h*128+d][k]
    __shared__ float part[2][128];
    int which = blk >> 2, h = blk & 3;
    int k = tid & 127, dh = tid >> 7;
    const float* W = which ? W_src : W_tgt;
    const float* att = which ? att_src : att_tgt;
    float acc = 0.f;
#pragma unroll 4
    for (int i = 0; i < 64; ++i) {
      int d = dh * 64 + i;
      acc += att[h * 128 + d] * W[(h * 128 + d) * 128 + k];
    }
    part[dh][k] = acc;
    __syncthreads();
    if (tid < 128) ws_c[(which * 4 + h) * 128 + k] = part[0][k] + part[1][k];
  } else if (blk < 200) {
    int i = (blk - 8) * 256 + tid;  // 0..49151
    int r = i >> 7, c = i & 127;
    float v = (r < 256) ? W_gv[i] : W_out[i - 32768];
    int mat = (r < 128) ? 0 : ((r < 256) ? 1 : 2);
    int n = r & 127, kg = c >> 3, j = c & 7;
    wpP[mat * 16384 + (kg * 128 + n) * 8 + j] = f2bf(v);
  } else {
    int i = (blk - 200) * 256 + tid;  // 0..65535
    int n = i >> 7, c = i & 127;
    int kg = c >> 3, j = c & 7;
    W_srcP[(kg * 512 + n) * 8 + j] = f2bf(W_src[i]);
  }
}

// ---------------- K_light: avec (a_tgt + ES/ES2) | adj bitmask. ZERO LDS. ----------------
__global__ __launch_bounds__(256) void k_light(
    const float* __restrict__ x_target, const float* __restrict__ x_source,
    const float* __restrict__ adj, const float* __restrict__ ws_c,
    float* __restrict__ a_tgtT, float* __restrict__ esrc,
    unsigned long long* __restrict__ abits) {
  int blk = blockIdx.x, tid = threadIdx.x;
  int w = tid >> 6, lane = tid & 63;
  if (blk < 4096) {
    // ---- avec: rows 0..16383 (tgt then src), one row per wave ----
    int row = blk * 4 + w;
    int is_src = row >> 13;
    int r = row & 8191;
    const float* xp = (is_src ? x_source : x_target) + (size_t)r * 128;
    float2 xv = *(const float2*)(xp + lane * 2);
    const float* c = ws_c + is_src * 512;
#pragma unroll
    for (int h = 0; h < 4; ++h) {
      float2 c2 = *(const float2*)(c + h * 128 + lane * 2);
      float p = xv.x * c2.x + xv.y * c2.y;
#pragma unroll
      for (int off = 32; off; off >>= 1) p += __shfl_xor(p, off);
      if (lane == 0) {
        int idx = (((r >> 10) * 4 + h) << 10) | (r & 1023);
        if (is_src) {
          float2 e = make_float2(__expf(p), __expf(0.2f * p));
          *(float2*)&esrc[(size_t)idx * 2] = e;
        } else {
          a_tgtT[idx] = p;
        }
      }
    }
  } else {
    // ---- adj -> bitmask, 4 rows per block ----
    int row = (blk - 4096) * 4 + w;  // 0..8191
    const float* ar = adj + (size_t)row * 1024;
#pragma unroll 4
    for (int it = 0; it < 16; ++it) {
      float A = ar[it * 64 + lane];
      unsigned long long bal = __ballot(A != 0.f);
      if (lane == 0) abits[row * 16 + it] = bal;
    }
  }
}

// ---------------- K_hsrc: h_srcP[b*4+h][s/8][d][8] = (x_source @ W_src^T) bf16 ----------
__global__ __launch_bounds__(256) void k_hsrc(
    const float* __restrict__ x_source,
    const unsigned short* __restrict__ W_srcP,
    unsigned short* __restrict__ h_srcP) {
  __shared__ unsigned short As[128][136];
  int mt = blockIdx.x >> 2, nt = blockIdx.x & 3;
  int nbase = nt * 128;
  int b = mt >> 3, sbase = (mt & 7) * 128;
  int tid = threadIdx.x;
  int w = tid >> 6, lane = tid & 63;
#pragma unroll
  for (int c = tid; c < 2048; c += 256) {
    int r = c >> 4, c8 = (c & 15) * 8;
    const float* src = x_source + ((size_t)(mt * 128 + r)) * 128 + c8;
    *(s16x8*)&As[r][c8] = pack8(*(const float4*)src, *(const float4*)(src + 4));
  }
  __syncthreads();
  int tl = lane & 31, q = lane >> 5;
  int wm = w >> 1, wn = w & 1;
  f32x16 acc00 = zero16(), acc01 = zero16(), acc10 = zero16(), acc11 = zero16();
#pragma unroll
  for (int kk = 0; kk < 8; ++kk) {
    int k = kk * 16 + q * 8;
    int kg = kk * 2 + q;
    s16x8 a0 = *(const s16x8*)&As[wm * 64 + tl][k];
    s16x8 a1 = *(const s16x8*)&As[wm * 64 + 32 + tl][k];
    s16x8 b0 = *(const s16x8*)(W_srcP + (size_t)(kg * 512 + nbase + wn * 64 + tl) * 8);
    s16x8 b1 = *(const s16x8*)(W_srcP + (size_t)(kg * 512 + nbase + wn * 64 + 32 + tl) * 8);
    acc00 = mfma_bf16(a0, b0, acc00);
    acc01 = mfma_bf16(a0, b1, acc01);
    acc10 = mfma_bf16(a1, b0, acc10);
    acc11 = mfma_bf16(a1, b1, acc11);
  }
  __syncthreads();
#pragma unroll
  for (int r = 0; r < 16; ++r) {
    int rp = (r & 3) + 8 * (r >> 2) + 4 * q;
    As[wn * 64 + tl][wm * 64 + rp] = f2bf(acc00[r]);
    As[wn * 64 + 32 + tl][wm * 64 + rp] = f2bf(acc01[r]);
    As[wn * 64 + tl][wm * 64 + 32 + rp] = f2bf(acc10[r]);
    As[wn * 64 + 32 + tl][wm * 64 + 32 + rp] = f2bf(acc11[r]);
  }
  __syncthreads();
  int hh = nbase >> 7;
  size_t base = ((size_t)(b * 4 + hh)) << 17;
#pragma unroll
  for (int c = tid; c < 2048; c += 256) {
    int d = c & 127, sgl = c >> 7;
    *(uint4*)(h_srcP + base + (size_t)((sbase >> 3) + sgl) * 1024 + d * 8) =
        *(const uint4*)&As[d][sgl * 8];
  }
}

// ---------------- K_attn: per-(b,head,t-tile) attention, separable exp ----------------
// grid 1024 = tt(32) x bh(32, low bits for XCD L2 locality); 4 waves = s-quarters.
__global__ __launch_bounds__(256, 4) void k_attn(
    const unsigned short* __restrict__ h_srcP,
    const float* __restrict__ a_tgtT, const float* __restrict__ esrc,
    const unsigned int* __restrict__ abits32,
    unsigned short* __restrict__ out_head) {
  __shared__ float smem[4096];         // phase A: es[s]{ES,ES2} 2048f; phase B: red[32][128]
  __shared__ unsigned int bmask[32][33];
  __shared__ float eab[32], ea2b[32], scb[32];
  __shared__ float zpart[4][32];
  int bh = blockIdx.x & 31, tt = blockIdx.x >> 5;
  int b = bh >> 2;
  int tbase = tt * 32;
  int tid = threadIdx.x, w = tid >> 6, lane = tid & 63;
  {
    const float* ep = esrc + ((size_t)bh << 11);
    *(float4*)&smem[tid * 8] = *(const float4*)(ep + tid * 8);
    *(float4*)&smem[tid * 8 + 4] = *(const float4*)(ep + tid * 8 + 4);
  }
  {
    int r = tid >> 3, c = tid & 7;
    uint4 v = *(const uint4*)(abits32 + ((size_t)(b * 1024 + tbase + r)) * 32 + c * 4);
    bmask[r][c * 4] = v.x; bmask[r][c * 4 + 1] = v.y;
    bmask[r][c * 4 + 2] = v.z; bmask[r][c * 4 + 3] = v.w;
  }
  if (tid < 32) {
    float at = a_tgtT[((size_t)bh << 10) + tbase + tid];
    eab[tid] = __expf(at);
    ea2b[tid] = __expf(0.2f * at);
  }
  __syncthreads();
  int sq = w, tl = lane & 31, q = lane >> 5;
  float EA = eab[tl], EA2 = ea2b[tl];
  f32x16 acc[4];
#pragma unroll
  for (int i = 0; i < 4; ++i) acc[i] = zero16();
  float z = 0.f;
  const unsigned short* bbase = h_srcP + ((size_t)bh << 17);
#pragma unroll 2
  for (int kk = 0; kk < 16; ++kk) {
    int sA = sq * 256 + kk * 16 + q * 8;
    const unsigned short* hp = bbase + (size_t)((sA >> 3) * 128 + tl) * 8;
    s16x8 b0 = *(const s16x8*)hp;
    s16x8 b1 = *(const s16x8*)(hp + 256);
    s16x8 b2 = *(const s16x8*)(hp + 512);
    s16x8 b3 = *(const s16x8*)(hp + 768);
    unsigned int wbits = bmask[tl][sA >> 5] >> (sA & 31);
    const float4* ev = (const float4*)&smem[sA * 2];
    float4 e0 = ev[0], e1 = ev[1], e2 = ev[2], e3 = ev[3];
    int4 afw;
#define PAIR(EV, J0, OUT)                                              \
  {                                                                    \
    float q1a = EA * EV.x, q0a = EA2 * EV.y;                           \
    float pa = (q1a >= 1.f) ? q1a : q0a;                               \
    unsigned pau = __float_as_uint(pa) & (0u - ((wbits >> (J0)) & 1u)); \
    float q1b = EA * EV.z, q0b = EA2 * EV.w;                           \
    float pb = (q1b >= 1.f) ? q1b : q0b;                               \
    unsigned pbu = __float_as_uint(pb) & (0u - ((wbits >> (J0 + 1)) & 1u)); \
    z += __uint_as_float(pau) + __uint_as_float(pbu);                  \
    OUT = (int)__builtin_amdgcn_perm(pbu + 0x8000u, pau + 0x8000u, 0x07060302u); \
  }
    PAIR(e0, 0, afw.x)
    PAIR(e1, 2, afw.y)
    PAIR(e2, 4, afw.z)
    PAIR(e3, 6, afw.w)
#undef PAIR
    s16x8 af = __builtin_bit_cast(s16x8, afw);
    acc[0] = mfma_bf16(af, b0, acc[0]);
    acc[1] = mfma_bf16(af, b1, acc[1]);
    acc[2] = mfma_bf16(af, b2, acc[2]);
    acc[3] = mfma_bf16(af, b3, acc[3]);
  }
  z += __shfl_xor(z, 32);
  if (q == 0) zpart[sq][tl] = z;
  __syncthreads();
  if (tid < 32) {
    float Z = zpart[0][tid] + zpart[1][tid] + zpart[2][tid] + zpart[3][tid];
    scb[tid] = (Z > 0.f) ? 0.25f / Z : 0.f;
  }
  float (*red)[128] = (float(*)[128])smem;
#pragma unroll
  for (int sqi = 0; sqi < 4; ++sqi) {
    __syncthreads();
    if (sq == sqi) {
#pragma unroll
      for (int dt = 0; dt < 4; ++dt)
#pragma unroll
        for (int r = 0; r < 16; ++r) {
          int rp = (r & 3) + 8 * (r >> 2) + 4 * q;
          if (sqi == 0)
            red[rp][dt * 32 + tl] = acc[dt][r];
          else
            red[rp][dt * 32 + tl] += acc[dt][r];
        }
    }
  }
  __syncthreads();
  {
    int idx = tid * 16;
    int r = idx >> 7, d0 = idx & 127;
    float sc = scb[r];
    s16x8 o0, o1;
#pragma unroll
    for (int i = 0; i < 8; ++i) {
      o0[i] = (short)f2bf(red[r][d0 + i] * sc);
      o1[i] = (short)f2bf(red[r][d0 + 8 + i] * sc);
    }
    size_t base = ((size_t)(bh & 3)) * 1048576 +
                  ((size_t)(b * 1024 + tbase + r)) * 128 + d0;
    *(s16x8*)(out_head + base) = o0;
    *(s16x8*)(out_head + base + 8) = o1;
  }
}

// ---------------- K_ffn: head-sum + bias + LN1 + SwiGLU FFN + LN2 (16 rows/block) ----
__global__ __launch_bounds__(256) void k_ffn(
    const float* __restrict__ x_target,
    const unsigned short* __restrict__ out_head,
    const float* __restrict__ gat_bias,
    const float* __restrict__ ln1_g, const float* __restrict__ ln1_b,
    const unsigned short* __restrict__ wpP,
    const float* __restrict__ ln2_g, const float* __restrict__ ln2_b,
    float* __restrict__ out) {
  __shared__ unsigned short x1s[16][136];
  __shared__ float x1f[16][128];
  __shared__ unsigned short hids[16][136];
  __shared__ float yred[16][128];
  int tid = threadIdx.x;
  int row = tid >> 4, k0 = (tid & 15) * 8;
  size_t gr = (size_t)blockIdx.x * 16 + row;
  // phase 1: u = x_target + bias + sum_h out_head; LN1
  {
    float u[8];
    float4 xa = *(const float4*)(x_target + gr * 128 + k0);
    float4 xb = *(const float4*)(x_target + gr * 128 + k0 + 4);
    float4 ba = *(const float4*)(gat_bias + k0);
    float4 bb = *(const float4*)(gat_bias + k0 + 4);
    u[0] = xa.x + ba.x; u[1] = xa.y + ba.y; u[2] = xa.z + ba.z; u[3] = xa.w + ba.w;
    u[4] = xb.x + bb.x; u[5] = xb.y + bb.y; u[6] = xb.z + bb.z; u[7] = xb.w + bb.w;
#pragma unroll
    for (int h = 0; h < 4; ++h) {
      s16x8 pa = *(const s16x8*)(out_head + (size_t)h * 1048576 + gr * 128 + k0);
#pragma unroll
      for (int i = 0; i < 8; ++i) u[i] += bf2f((unsigned short)pa[i]);
    }
    float s = 0.f, ss = 0.f;
#pragma unroll
    for (int i = 0; i < 8; ++i) { s += u[i]; ss += u[i] * u[i]; }
#pragma unroll
    for (int off = 1; off < 16; off <<= 1) { s += __shfl_xor(s, off); ss += __shfl_xor(ss, off); }
    float mu = s * (1.f / 128.f);
    float var = ss * (1.f / 128.f) - mu * mu;
    float rstd = rsqrtf(var + 1e-5f);
#pragma unroll
    for (int i = 0; i < 8; ++i) {
      float xv = (u[i] - mu) * rstd * ln1_g[k0 + i] + ln1_b[k0 + i];
      x1s[row][k0 + i] = f2bf(xv);
      x1f[row][k0 + i] = xv;
    }
  }
  __syncthreads();
  int w = tid >> 6, lane = tid & 63, n16 = lane & 15, q2 = lane >> 4;
  int nb = w * 32;
  // GEMM1 (16x16x32): val n in [nb,nb+32); gate = same n at wpP + 16384 elements
  f32x4 accv0 = zero4(), accv1 = zero4(), accg0 = zero4(), accg1 = zero4();
#pragma unroll
  for (int kk = 0; kk < 4; ++kk) {
    s16x8 a = *(const s16x8*)&x1s[n16][kk * 32 + q2 * 8];
    int kg = kk * 4 + q2;
    const unsigned short* bp = wpP + (size_t)(kg * 128 + nb + n16) * 8;
    accv0 = mfma16(a, *(const s16x8*)bp, accv0);
    accv1 = mfma16(a, *(const s16x8*)(bp + 128), accv1);
    accg0 = mfma16(a, *(const s16x8*)(bp + 16384), accg0);
    accg1 = mfma16(a, *(const s16x8*)(bp + 16384 + 128), accg1);
  }
#pragma unroll
  for (int r = 0; r < 4; ++r) {
    int m = q2 * 4 + r;
    float g0 = accg0[r], g1 = accg1[r];
    float h0 = accv0[r] * g0 / (1.f + __expf(-g0));
    float h1 = accv1[r] * g1 / (1.f + __expf(-g1));
    hids[m][nb + n16] = f2bf(h0);
    hids[m][nb + 16 + n16] = f2bf(h1);
  }
  __syncthreads();
  // GEMM2: out n in [nb, nb+32)
  f32x4 acco0 = zero4(), acco1 = zero4();
#pragma unroll
  for (int kk = 0; kk < 4; ++kk) {
    s16x8 a = *(const s16x8*)&hids[n16][kk * 32 + q2 * 8];
    int kg = kk * 4 + q2;
    const unsigned short* bp = wpP + 32768 + (size_t)(kg * 128 + nb + n16) * 8;
    acco0 = mfma16(a, *(const s16x8*)bp, acco0);
    acco1 = mfma16(a, *(const s16x8*)(bp + 128), acco1);
  }
#pragma unroll
  for (int r = 0; r < 4; ++r) {
    int m = q2 * 4 + r;
    yred[m][nb + n16] = x1f[m][nb + n16] + acco0[r];
    yred[m][nb + 16 + n16] = x1f[m][nb + 16 + n16] + acco1[r];
  }
  __syncthreads();
  // LN2 + store
  {
    float y[8];
#pragma unroll
    for (int i = 0; i < 8; ++i) y[i] = yred[row][k0 + i];
    float s = 0.f, ss = 0.f;
#pragma unroll
    for (int i = 0; i < 8; ++i) { s += y[i]; ss += y[i] * y[i]; }
#pragma unroll
    for (int off = 1; off < 16; off <<= 1) { s += __shfl_xor(s, off); ss += __shfl_xor(ss, off); }
    float mu = s * (1.f / 128.f);
    float var = ss * (1.f / 128.f) - mu * mu;
    float rstd = rsqrtf(var + 1e-5f);
    float4 o0, o1;
    o0.x = (y[0] - mu) * rstd * ln2_g[k0] + ln2_b[k0];
    o0.y = (y[1] - mu) * rstd * ln2_g[k0 + 1] + ln2_b[k0 + 1];
    o0.z = (y[2] - mu) * rstd * ln2_g[k0 + 2] + ln2_b[k0 + 2];
    o0.w = (y[3] - mu) * rstd * ln2_g[k0 + 3] + ln2_b[k0 + 3];
    o1.x = (y[4] - mu) * rstd * ln2_g[k0 + 4] + ln2_b[k0 + 4];
    o1.y = (y[5] - mu) * rstd * ln2_g[k0 + 5] + ln2_b[k0 + 5];
    o1.z = (y[6] - mu) * rstd * ln2_g[k0 + 6] + ln2_b[k0 + 6];
    o1.w = (y[7] - mu) * rstd * ln2_g[k0 + 7] + ln2_b[k0 + 7];
    *(float4*)(out + gr * 128 + k0) = o0;
    *(float4*)(out + gr * 128 + k0 + 4) = o1;
  }
}

// ---------------- launch ----------------
extern "C" void kernel_launch(void* const* d_in, const int* in_sizes, int n_in,
                              void* d_out, int out_size, void* d_ws, size_t ws_size,
                              hipStream_t stream) {
  const float* x_target = (const float*)d_in[0];
  const float* adj      = (const float*)d_in[1];
  const float* x_source = (const float*)d_in[2];
  const float* W_src    = (const float*)d_in[3];
  const float* W_tgt    = (const float*)d_in[4];
  const float* att_src  = (const float*)d_in[5];
  const float* att_tgt  = (const float*)d_in[6];
  const float* gat_bias = (const float*)d_in[7];
  const float* ln1_g    = (const float*)d_in[8];
  const float* ln1_b    = (const float*)d_in[9];
  const float* W_gv     = (const float*)d_in[10];
  const float* W_out    = (const float*)d_in[11];
  const float* ln2_g    = (const float*)d_in[12];
  const float* ln2_b    = (const float*)d_in[13];

  float* ws_f = (float*)d_ws;
  // workspace layout (float-element offsets)
  const size_t OFF_C  = 0;        // csum [2][4][128] = 1024 f
  const size_t OFF_AT = 1024;     // a_tgtT [8][4][1024] = 32768 f
  const size_t OFF_ES = 33792;    // esrc float2 [8][4][1024] = 65536 f
  const size_t OFF_AB = 99328;    // abits u64 [8192][16] = 262144 f
  const size_t OFF_OH = 361472;   // out_head bf16 [4][8192][128] = 2097152 f
  const size_t OFF_HS = 2458624;  // h_srcP bf16 [32][131072] = 2097152 f
  unsigned short* h_srcP = (unsigned short*)(ws_f + OFF_HS);
  unsigned short* wpP    = h_srcP + (size_t)4194304;  // 49152 bf16
  unsigned short* W_srcP = wpP + 49152;               // 65536 bf16

  k_prep<<<456, 256, 0, stream>>>(W_tgt, W_src, att_tgt, att_src, W_gv, W_out,
                                  ws_f + OFF_C, wpP, W_srcP);
  k_light<<<6144, 256, 0, stream>>>(x_target, x_source, adj, ws_f + OFF_C,
                                    ws_f + OFF_AT, ws_f + OFF_ES,
                                    (unsigned long long*)(ws_f + OFF_AB));
  k_hsrc<<<256, 256, 0, stream>>>(x_source, W_srcP, h_srcP);
  k_attn<<<1024, 256, 0, stream>>>(h_srcP, ws_f + OFF_AT, ws_f + OFF_ES,
                                   (const unsigned int*)(ws_f + OFF_AB),
                                   (unsigned short*)(ws_f + OFF_OH));
  k_ffn<<<512, 256, 0, stream>>>(x_target, (const unsigned short*)(ws_f + OFF_OH),
                                 gat_bias, ln1_g, ln1_b, wpP, ln2_g, ln2_b,
                                 (float*)d_out);
}